// Round 3
// baseline (405.934 us; speedup 1.0000x reference)
//
#include <hip/hip_runtime.h>
#include <math.h>

#define BISECT_ITERS 60
#define N_ROWS 131072

// float-rounded versions of python doubles (match numpy scalar->f32 cast)
#define E_CONST 2.71828182845904523536f       // float(np.e)
#define SMALL_THRESH 5.65685424949238019520f  // 4*sqrt(2)

// ---------------------------------------------------------------------------
// Correctly-rounded fp32 natural log.
// Input wc in [1e-12f, ~1e4] (positive, normal, finite — guaranteed by caller).
// Computed in double via 2*atanh((m-1)/(m+1)) series, rel err ~1e-14, then
// rounded once to fp32 -> correctly-rounded fp32 log, within <=1 ulp of
// numpy's vectorized logf (same mismatch class jax has vs np).
// ---------------------------------------------------------------------------
__device__ __forceinline__ float log_cr(float wc) {
    double d = (double)wc;
    long long b = __double_as_longlong(d);
    int e = (int)((b >> 52) & 0x7FF) - 1023;
    double m = __longlong_as_double((b & 0x000FFFFFFFFFFFFFLL) |
                                    0x3FF0000000000000LL);  // m in [1,2)
    if (m > 1.3333333333333333) {  // reduce to m in [2/3, 4/3) -> |s| <= 0.2
        m *= 0.5;
        e += 1;
    }
    double s = (m - 1.0) / (m + 1.0);
    double s2 = s * s;
    double p = 1.0 / 17.0;
    p = fma(p, s2, 1.0 / 15.0);
    p = fma(p, s2, 1.0 / 13.0);
    p = fma(p, s2, 1.0 / 11.0);
    p = fma(p, s2, 1.0 / 9.0);
    p = fma(p, s2, 1.0 / 7.0);
    p = fma(p, s2, 1.0 / 5.0);
    p = fma(p, s2, 1.0 / 3.0);
    p = fma(p, s2, 1.0);
    double res = fma(2.0 * s, p, (double)e * 0.69314718055994530941723212145818);
    return (float)res;
}

__device__ __forceinline__ float safe_log_f(float w) {
    // np: log(maximum(w, 1e-12)) — max in fp32 first
    return log_cr(fmaxf(w, 1e-12f));
}

// ---------------------------------------------------------------------------
// fp32 pieces, numpy op-order, IEEE ops, no contraction
// ---------------------------------------------------------------------------
__device__ __forceinline__ float clip1f(float x) {
#pragma clang fp contract(off)
    return fminf(fmaxf(x, -1.0f), 1.0f);
}

__device__ __forceinline__ float sl1(float x) {  // smooth_l1, beta=1
#pragma clang fp contract(off)
    float d = fabsf(x);
    return (d < 1.0f) ? (0.5f * d) * d : d - 0.5f;
}

__device__ __forceinline__ float eps_f(float w, float wh, float lwp) {
#pragma clang fp contract(off)
    return sl1((w - wh) * 0.5f) + sl1(safe_log_f(w) - lwp);
}

__device__ __forceinline__ float eps_prime_f(float w, float wh, float lwp) {
#pragma clang fp contract(off)
    float x = (w - wh) * 0.5f;
    float diff = safe_log_f(w) - lwp;
    return 0.5f * clip1f(x) + clip1f(diff) / fmaxf(w, 1e-12f);  // IEEE div
}

__device__ __forceinline__ float sigma_f(float w, float wh, float lwp) {
#pragma clang fp contract(off)
    return w * eps_prime_f(w, wh, lwp);
}

// ---------- _find_min with f = eps_prime ----------
__device__ float find_min_e(float u, float v, float wh, float lwp) {
#pragma clang fp contract(off)
    float u0 = u, v0 = v;
#pragma unroll 1
    for (int i = 0; i < BISECT_ITERS; ++i) {
        float m = (u + v) * 0.5f;
        bool c = eps_prime_f(m, wh, lwp) >= 0.0f;
        u = c ? u : m;
        v = c ? m : v;
    }
    float m = (u + v) * 0.5f;
    float r = m;
    if (eps_prime_f(v0, wh, lwp) <= 0.0f) r = v0;
    if (eps_prime_f(u0, wh, lwp) >= 0.0f) r = u0;  // u0 takes precedence
    return r;
}

// ---------- _find_min with f = sigma ----------
__device__ float find_min_s(float u, float v, float wh, float lwp) {
#pragma clang fp contract(off)
    float u0 = u, v0 = v;
#pragma unroll 1
    for (int i = 0; i < BISECT_ITERS; ++i) {
        float m = (u + v) * 0.5f;
        bool c = sigma_f(m, wh, lwp) >= 0.0f;
        u = c ? u : m;
        v = c ? m : v;
    }
    float m = (u + v) * 0.5f;
    float r = m;
    if (sigma_f(v0, wh, lwp) <= 0.0f) r = v0;
    if (sigma_f(u0, wh, lwp) >= 0.0f) r = u0;
    return r;
}

// a1,b1 only enter _solve_o1 via w0 = b1 - a1, so pass w0 directly.
__device__ __attribute__((noinline)) float solve_o1(float wp, float wh, float w0) {
#pragma clang fp contract(off)
    bool branchA = fmaxf(w0, wh) < wp;
    bool branchB = fmaxf(w0, wp) < wh;
    float lwp = safe_log_f(wp);
    float ewp = E_CONST * wp;

    float cA = find_min_e(fmaxf(w0, wh), wp, wh, lwp);
    float c2 = find_min_e(fmaxf(w0, wp), fminf(ewp, wh), wh, lwp);
    float c3 = find_min_e(fmaxf(fmaxf(w0, 2.0f), fmaxf(wh - 2.0f, ewp)), wh,
                          wh, lwp);

    float base = fmaxf(w0, fmaxf(wh - 2.0f, ewp));
    float c4 = find_min_s(base, fminf(E_CONST, wh), wh, lwp);

    float disc = sqrtf(fmaxf(1.0f - 32.0f / fmaxf(wh * wh, 1e-12f), 0.0f));
    float c5 = find_min_s(base,
                          fminf(fminf(ewp, wh), (wh * 0.25f) * (1.0f + disc)),
                          wh, lwp);
    float c6 = find_min_s(fmaxf(base, (wh * 0.25f) * (1.0f - disc)),
                          fminf(ewp, wh), wh, lwp);

    bool small_ = wh <= SMALL_THRESH;
    float cands[7] = {w0, wh, c2, c3, c4, c5, c6};
    float evals[7];
    evals[0] = eps_f(w0, wh, lwp);
    evals[1] = eps_f(wh, wh, lwp);
    evals[2] = eps_f(c2, wh, lwp);
    evals[3] = eps_f(c3, wh, lwp);
    evals[4] = (!small_) ? 1e30f : eps_f(c4, wh, lwp);
    evals[5] = small_ ? 1e30f : eps_f(c5, wh, lwp);
    evals[6] = small_ ? 1e30f : eps_f(c6, wh, lwp);

    // np.argmin: first minimum wins; comparisons in fp32
    float bestv = evals[0];
    float wB = cands[0];
#pragma unroll
    for (int j = 1; j < 7; ++j) {
        if (evals[j] < bestv) {
            bestv = evals[j];
            wB = cands[j];
        }
    }

    return branchA ? cA : (branchB ? wB : w0);
}

__global__ __launch_bounds__(256)
void cabb_solver_kernel(const float* __restrict__ pred,
                        const float* __restrict__ target,
                        const float* __restrict__ crop,
                        const float* __restrict__ prop,
                        const int* __restrict__ cases,
                        float* __restrict__ out, int n) {
#pragma clang fp contract(off)
    int tid = blockIdx.x * blockDim.x + threadIdx.x;
    if (tid >= 2 * n) return;
    int row = tid >> 1;
    int axis = tid & 1;
    int d_id = axis;
    int o_id = axis + 2;
    int r4 = row * 4;

    float pd = pred[r4 + d_id];
    float po = (float)exp((double)pred[r4 + o_id]);  // correctly-rounded fp32 exp
    float td = target[r4 + d_id];
    float to = (float)exp((double)target[r4 + o_id]);
    float p_d = prop[r4 + d_id];
    float p_o = prop[r4 + o_id];
    float ca = 0.5f * (p_d + p_o);
    float da = p_o - p_d;
    float crop_a = crop[r4 + axis];  // crop[:, axis] == crop[:, d_id]
    int lt = cases[r4 + 2 * axis];
    int rb = cases[r4 + 2 * axis + 1];

    float a1r = td - 0.5f * to;
    float b1r = (crop_a - ca) / da;  // == b2 in the 'both' path
    float a1l = (-ca) / da;
    float b1l = td + 0.5f * to;

    bool need_r = (!lt) && rb;
    bool need_l = lt && (!rb);
    bool need_b = lt && rb;

    // ---- unified first solve: r, l, and b lanes run ONE solve_o1 body ----
    float wp_1, wh_1, w0_1;
    if (need_b) {
        wp_1 = pd;                   // _solve_o2(pd, pd, ...): wp = pd
        wh_1 = 2.0f * (pd - a1l);    // wh1 = 2*(dp - a2)
        w0_1 = b1r - a1l;            // w0 = b2 - a2
    } else if (need_l) {
        wp_1 = po;
        wh_1 = 2.0f * (b1l - pd);
        w0_1 = b1l - a1l;
    } else {  // r (and harmless dummy for 'none' lanes)
        wp_1 = po;
        wh_1 = 2.0f * (pd - a1r);
        w0_1 = b1r - a1r;
    }
    float s1 = solve_o1(wp_1, wh_1, w0_1);

    // ---- second solve: only 'both' lanes ----
    float s2 = 0.0f;
    if (need_b) {
        s2 = solve_o1(pd, 2.0f * (b1r - pd), b1r - a1l);  // wh2 = 2*(b2 - dp)
    }

    float d_lab, w_lab;
    if (need_b) {
        float wh1 = 2.0f * (pd - a1l);
        float wh2 = 2.0f * (b1r - pd);
        bool trivial = pd >= fmaxf(wh1, wh2);  // wp = pd
        float lwp = safe_log_f(pd);
        bool pick1 = eps_f(s1, wh1, lwp) <= eps_f(s2, wh2, lwp);
        float dd = pick1 ? (a1l + 0.5f * s1) : (b1r + 0.5f * s2);
        float ww = pick1 ? s1 : s2;
        d_lab = trivial ? pd : dd;
        w_lab = trivial ? pd : ww;
    } else if (need_l) {
        d_lab = b1l - 0.5f * s1;
        w_lab = s1;
    } else if (need_r) {
        d_lab = a1r + 0.5f * s1;
        w_lab = s1;
    } else {
        d_lab = td;
        w_lab = to;
    }

    out[r4 + axis] = d_lab;      // d0 / d1
    out[r4 + 2 + axis] = w_lab;  // w0 / w1
}

extern "C" void kernel_launch(void* const* d_in, const int* in_sizes, int n_in,
                              void* d_out, int out_size, void* d_ws, size_t ws_size,
                              hipStream_t stream) {
    // Input order (setup_inputs dict): img, pred, target, crop_shapes,
    // proposal_list, cases, sampling_results
    const float* pred = (const float*)d_in[1];
    const float* target = (const float*)d_in[2];
    const float* crop = (const float*)d_in[3];
    const float* prop = (const float*)d_in[4];
    const int* cases = (const int*)d_in[5];
    float* out = (float*)d_out;

    int n = N_ROWS;
    int threads = 2 * n;
    int block = 256;
    int grid = (threads + block - 1) / block;
    cabb_solver_kernel<<<grid, block, 0, stream>>>(pred, target, crop, prop,
                                                   cases, out, n);
}

// Round 4
// 139.380 us; speedup vs baseline: 2.9124x; 2.9124x over previous
//
#include <hip/hip_runtime.h>
#include <math.h>

#define BISECT_ITERS 60
#define N_ROWS 131072

// float-rounded versions of python doubles (match numpy scalar->f32 cast)
#define E_CONST 2.71828182845904523536f       // float(np.e)
#define SMALL_THRESH 5.65685424949238019520f  // 4*sqrt(2)
#define LN2F 0.69314718055994530942f

// ---------------------------------------------------------------------------
// Correctly-rounded fp32 natural log (double atanh-series, round once).
// Used ONLY at decision points: candidate evals, endpoint overrides, lwp,
// pick1. This path gave absmax 0.0 vs numpy in round 3 — do not touch.
// ---------------------------------------------------------------------------
__device__ __forceinline__ float log_cr(float wc) {
    double d = (double)wc;
    long long b = __double_as_longlong(d);
    int e = (int)((b >> 52) & 0x7FF) - 1023;
    double m = __longlong_as_double((b & 0x000FFFFFFFFFFFFFLL) |
                                    0x3FF0000000000000LL);  // m in [1,2)
    if (m > 1.3333333333333333) {  // reduce to m in [2/3, 4/3) -> |s| <= 0.2
        m *= 0.5;
        e += 1;
    }
    double s = (m - 1.0) / (m + 1.0);
    double s2 = s * s;
    double p = 1.0 / 17.0;
    p = fma(p, s2, 1.0 / 15.0);
    p = fma(p, s2, 1.0 / 13.0);
    p = fma(p, s2, 1.0 / 11.0);
    p = fma(p, s2, 1.0 / 9.0);
    p = fma(p, s2, 1.0 / 7.0);
    p = fma(p, s2, 1.0 / 5.0);
    p = fma(p, s2, 1.0 / 3.0);
    p = fma(p, s2, 1.0);
    double res = fma(2.0 * s, p, (double)e * 0.69314718055994530941723212145818);
    return (float)res;
}

__device__ __forceinline__ float safe_log_f(float w) {
    return log_cr(fmaxf(w, 1e-12f));
}

__device__ __forceinline__ float clip1f(float x) {
#pragma clang fp contract(off)
    return fminf(fmaxf(x, -1.0f), 1.0f);
}

__device__ __forceinline__ float sl1(float x) {  // smooth_l1, beta=1
#pragma clang fp contract(off)
    float d = fabsf(x);
    return (d < 1.0f) ? (0.5f * d) * d : d - 0.5f;
}

// cr eval: numpy op-order, IEEE fp32, no contraction
__device__ __forceinline__ float eps_f(float w, float wh, float lwp) {
#pragma clang fp contract(off)
    return sl1((w - wh) * 0.5f) + sl1(safe_log_f(w) - lwp);
}

__device__ __forceinline__ float eps_prime_cr(float w, float wh, float lwp) {
#pragma clang fp contract(off)
    float x = (w - wh) * 0.5f;
    float diff = safe_log_f(w) - lwp;
    return 0.5f * clip1f(x) + clip1f(diff) / fmaxf(w, 1e-12f);  // IEEE div
}

__device__ __forceinline__ float sigma_cr(float w, float wh, float lwp) {
#pragma clang fp contract(off)
    return w * eps_prime_cr(w, wh, lwp);
}

// ---------------------------------------------------------------------------
// FAST inner-loop sign of eps_prime: multiply through by max(m,1e-12) > 0
// (kills the IEEE div) and use native v_log_f32. Sign differs from numpy's
// fp32 eps_prime only where |f| is within ulps of 0 — i.e. in the last
// bisection steps — shifting the converged root by ~ulps. eps is stationary
// at every converged root, so fp32 cr evals of those candidates are
// bit-identical and all decisions stay numpy-exact.
// ---------------------------------------------------------------------------
__device__ __forceinline__ float epsp_sign(float m, float wh, float lwp) {
    float wm = fmaxf(m, 1e-12f);
    float x = (m - wh) * 0.5f;
    float diff = __builtin_fmaf(LN2F, __builtin_amdgcn_logf(wm), -lwp);
    return __builtin_fmaf(0.5f * clip1f(x), wm, clip1f(diff));
}

// ---------- _find_min with f = eps_prime ----------
// Early break: once m == u or m == v, the (u,v) state is provably constant
// for all remaining iterations (m recomputes identically), so breaking
// reproduces numpy's iteration-60 state exactly. Wave-uniform via __all.
__device__ float find_min_e(float u, float v, float wh, float lwp) {
#pragma clang fp contract(off)
    float u0 = u, v0 = v;
#pragma unroll 1
    for (int i = 0; i < BISECT_ITERS; ++i) {
        float m = (u + v) * 0.5f;
        bool frozen = (m == u) || (m == v);
        bool c = epsp_sign(m, wh, lwp) >= 0.0f;
        u = c ? u : m;
        v = c ? m : v;
        if (__all(frozen)) break;
    }
    float m = (u + v) * 0.5f;
    float r = m;
    if (eps_prime_cr(v0, wh, lwp) <= 0.0f) r = v0;
    if (eps_prime_cr(u0, wh, lwp) >= 0.0f) r = u0;  // u0 takes precedence
    return r;
}

// ---------- _find_min with f = sigma ----------
// sign(sigma) = sign(m * eps_prime) = sign(m * epsp_sign) since the
// multiplied-through factor max(m,1e-12) is positive.
__device__ float find_min_s(float u, float v, float wh, float lwp) {
#pragma clang fp contract(off)
    float u0 = u, v0 = v;
#pragma unroll 1
    for (int i = 0; i < BISECT_ITERS; ++i) {
        float m = (u + v) * 0.5f;
        bool frozen = (m == u) || (m == v);
        bool c = (m * epsp_sign(m, wh, lwp)) >= 0.0f;
        u = c ? u : m;
        v = c ? m : v;
        if (__all(frozen)) break;
    }
    float m = (u + v) * 0.5f;
    float r = m;
    if (sigma_cr(v0, wh, lwp) <= 0.0f) r = v0;
    if (sigma_cr(u0, wh, lwp) >= 0.0f) r = u0;
    return r;
}

// a1,b1 only enter _solve_o1 via w0 = b1 - a1, so pass w0 directly.
__device__ __attribute__((noinline)) float solve_o1(float wp, float wh, float w0) {
#pragma clang fp contract(off)
    bool branchA = fmaxf(w0, wh) < wp;
    bool branchB = fmaxf(w0, wp) < wh;
    float lwp = safe_log_f(wp);
    float ewp = E_CONST * wp;

    float cA = find_min_e(fmaxf(w0, wh), wp, wh, lwp);
    float c2 = find_min_e(fmaxf(w0, wp), fminf(ewp, wh), wh, lwp);
    float c3 = find_min_e(fmaxf(fmaxf(w0, 2.0f), fmaxf(wh - 2.0f, ewp)), wh,
                          wh, lwp);

    float base = fmaxf(w0, fmaxf(wh - 2.0f, ewp));
    float c4 = find_min_s(base, fminf(E_CONST, wh), wh, lwp);

    float disc = sqrtf(fmaxf(1.0f - 32.0f / fmaxf(wh * wh, 1e-12f), 0.0f));
    float c5 = find_min_s(base,
                          fminf(fminf(ewp, wh), (wh * 0.25f) * (1.0f + disc)),
                          wh, lwp);
    float c6 = find_min_s(fmaxf(base, (wh * 0.25f) * (1.0f - disc)),
                          fminf(ewp, wh), wh, lwp);

    bool small_ = wh <= SMALL_THRESH;
    float cands[7] = {w0, wh, c2, c3, c4, c5, c6};
    float evals[7];
    evals[0] = eps_f(w0, wh, lwp);
    evals[1] = eps_f(wh, wh, lwp);
    evals[2] = eps_f(c2, wh, lwp);
    evals[3] = eps_f(c3, wh, lwp);
    evals[4] = (!small_) ? 1e30f : eps_f(c4, wh, lwp);
    evals[5] = small_ ? 1e30f : eps_f(c5, wh, lwp);
    evals[6] = small_ ? 1e30f : eps_f(c6, wh, lwp);

    // np.argmin: first minimum wins; comparisons in fp32
    float bestv = evals[0];
    float wB = cands[0];
#pragma unroll
    for (int j = 1; j < 7; ++j) {
        if (evals[j] < bestv) {
            bestv = evals[j];
            wB = cands[j];
        }
    }

    return branchA ? cA : (branchB ? wB : w0);
}

__global__ __launch_bounds__(256)
void cabb_solver_kernel(const float* __restrict__ pred,
                        const float* __restrict__ target,
                        const float* __restrict__ crop,
                        const float* __restrict__ prop,
                        const int* __restrict__ cases,
                        float* __restrict__ out, int n) {
#pragma clang fp contract(off)
    int tid = blockIdx.x * blockDim.x + threadIdx.x;
    if (tid >= 2 * n) return;
    int row = tid >> 1;
    int axis = tid & 1;
    int d_id = axis;
    int o_id = axis + 2;
    int r4 = row * 4;

    float pd = pred[r4 + d_id];
    float po = (float)exp((double)pred[r4 + o_id]);  // correctly-rounded fp32 exp
    float td = target[r4 + d_id];
    float to = (float)exp((double)target[r4 + o_id]);
    float p_d = prop[r4 + d_id];
    float p_o = prop[r4 + o_id];
    float ca = 0.5f * (p_d + p_o);
    float da = p_o - p_d;
    float crop_a = crop[r4 + axis];  // crop[:, axis] == crop[:, d_id]
    int lt = cases[r4 + 2 * axis];
    int rb = cases[r4 + 2 * axis + 1];

    float a1r = td - 0.5f * to;
    float b1r = (crop_a - ca) / da;  // == b2 in the 'both' path
    float a1l = (-ca) / da;
    float b1l = td + 0.5f * to;

    bool need_r = (!lt) && rb;
    bool need_l = lt && (!rb);
    bool need_b = lt && rb;

    // ---- unified first solve: r, l, and b lanes run ONE solve_o1 body ----
    float wp_1, wh_1, w0_1;
    if (need_b) {
        wp_1 = pd;                   // _solve_o2(pd, pd, ...): wp = pd
        wh_1 = 2.0f * (pd - a1l);    // wh1 = 2*(dp - a2)
        w0_1 = b1r - a1l;            // w0 = b2 - a2
    } else if (need_l) {
        wp_1 = po;
        wh_1 = 2.0f * (b1l - pd);
        w0_1 = b1l - a1l;
    } else {  // r (and harmless dummy for 'none' lanes)
        wp_1 = po;
        wh_1 = 2.0f * (pd - a1r);
        w0_1 = b1r - a1r;
    }
    float s1 = solve_o1(wp_1, wh_1, w0_1);

    // ---- second solve: only 'both' lanes ----
    float s2 = 0.0f;
    if (need_b) {
        s2 = solve_o1(pd, 2.0f * (b1r - pd), b1r - a1l);  // wh2 = 2*(b2 - dp)
    }

    float d_lab, w_lab;
    if (need_b) {
        float wh1 = 2.0f * (pd - a1l);
        float wh2 = 2.0f * (b1r - pd);
        bool trivial = pd >= fmaxf(wh1, wh2);  // wp = pd
        float lwp = safe_log_f(pd);
        bool pick1 = eps_f(s1, wh1, lwp) <= eps_f(s2, wh2, lwp);
        float dd = pick1 ? (a1l + 0.5f * s1) : (b1r + 0.5f * s2);
        float ww = pick1 ? s1 : s2;
        d_lab = trivial ? pd : dd;
        w_lab = trivial ? pd : ww;
    } else if (need_l) {
        d_lab = b1l - 0.5f * s1;
        w_lab = s1;
    } else if (need_r) {
        d_lab = a1r + 0.5f * s1;
        w_lab = s1;
    } else {
        d_lab = td;
        w_lab = to;
    }

    out[r4 + axis] = d_lab;      // d0 / d1
    out[r4 + 2 + axis] = w_lab;  // w0 / w1
}

extern "C" void kernel_launch(void* const* d_in, const int* in_sizes, int n_in,
                              void* d_out, int out_size, void* d_ws, size_t ws_size,
                              hipStream_t stream) {
    // Input order (setup_inputs dict): img, pred, target, crop_shapes,
    // proposal_list, cases, sampling_results
    const float* pred = (const float*)d_in[1];
    const float* target = (const float*)d_in[2];
    const float* crop = (const float*)d_in[3];
    const float* prop = (const float*)d_in[4];
    const int* cases = (const int*)d_in[5];
    float* out = (float*)d_out;

    int n = N_ROWS;
    int threads = 2 * n;
    int block = 256;
    int grid = (threads + block - 1) / block;
    cabb_solver_kernel<<<grid, block, 0, stream>>>(pred, target, crop, prop,
                                                   cases, out, n);
}